// Round 1
// baseline (1294.181 us; speedup 1.0000x reference)
//
#include <hip/hip_runtime.h>

#define D 128
#define DP 132  // LDS row stride (floats): +4 pad -> 8-distinct ds_read_b128 at
                // stride 2*DP*4 lands 2-way per bank (free, m136); 528B row is
                // still 16B-aligned so float4 row casts stay legal.
#define TM 16   // fused layer tile: 16 nodes, ~16.5 KB LDS -> 8 blocks/CU

// ---------------- CSR build ----------------

__global__ void hist_kernel(const int* __restrict__ dst, int* __restrict__ deg, int E) {
    int i = blockIdx.x * blockDim.x + threadIdx.x;
    if (i < E) atomicAdd(&deg[dst[i]], 1);
}

__global__ void scan1_kernel(const int* __restrict__ deg, int* __restrict__ local_excl,
                             int* __restrict__ blocksum, int n) {
    __shared__ int tmp[1024];
    int i = blockIdx.x * 1024 + threadIdx.x;
    int v = (i < n) ? deg[i] : 0;
    tmp[threadIdx.x] = v;
    __syncthreads();
    for (int off = 1; off < 1024; off <<= 1) {
        int t = 0;
        if (threadIdx.x >= off) t = tmp[threadIdx.x - off];
        __syncthreads();
        if (threadIdx.x >= off) tmp[threadIdx.x] += t;
        __syncthreads();
    }
    int incl = tmp[threadIdx.x];
    if (i < n) local_excl[i] = incl - v;
    if (threadIdx.x == 1023) blocksum[blockIdx.x] = tmp[1023];
}

__global__ void scan2_kernel(int* __restrict__ blocksum, int nb) {
    __shared__ int tmp[1024];
    int v = (threadIdx.x < nb) ? blocksum[threadIdx.x] : 0;
    tmp[threadIdx.x] = v;
    __syncthreads();
    for (int off = 1; off < 1024; off <<= 1) {
        int t = 0;
        if (threadIdx.x >= off) t = tmp[threadIdx.x - off];
        __syncthreads();
        if (threadIdx.x >= off) tmp[threadIdx.x] += t;
        __syncthreads();
    }
    if (threadIdx.x < nb) blocksum[threadIdx.x] = tmp[threadIdx.x] - v;  // exclusive
}

__global__ void scan3_kernel(const int* __restrict__ deg, const int* __restrict__ local_excl,
                             const int* __restrict__ blocksum, int* __restrict__ row_start,
                             int* __restrict__ cursor, float* __restrict__ inv_deg,
                             int n, int n_edges) {
    int i = blockIdx.x * 1024 + threadIdx.x;
    if (i < n) {
        int rs = local_excl[i] + blocksum[blockIdx.x];
        row_start[i] = rs;
        cursor[i]    = rs;
        inv_deg[i]   = 1.0f / fmaxf((float)deg[i], 1.0f);
    }
    if (i == 0) row_start[n] = n_edges;
}

// csr[] holds BYTE offsets of the source row (src * D * 4).
__global__ void scatter_kernel(const int* __restrict__ src, const int* __restrict__ dst,
                               int* __restrict__ cursor, int* __restrict__ csr, int E) {
    int i = blockIdx.x * blockDim.x + threadIdx.x;
    if (i < E) {
        int d = dst[i];
        int p = atomicAdd(&cursor[d], 1);
        csr[p] = src[i] << 9;   // * 512 bytes per row
    }
}

// ---------------- weight transpose (W[l][f][k] -> Wt[l][k][f]) ----------------

__global__ void transpose_w(const float* __restrict__ Wl, const float* __restrict__ Wr,
                            float* __restrict__ Wlt, float* __restrict__ Wrt, int total) {
    int i = blockIdx.x * blockDim.x + threadIdx.x;
    if (i < total) {
        int l = i >> 14;
        int r = i & 16383;
        int f = r >> 7;
        int k = r & 127;
        int o = (l << 14) + (k << 7) + f;
        Wlt[o] = Wl[i];
        Wrt[o] = Wr[i];
    }
}

// ---------------- fused SAGE layer ----------------
// Phase A: r2's proven gather (8 row loads in flight/wave).
// Phase B (r10 change): feature-sliced waves. Wave w computes feature
// columns [32w, 32w+32) for ALL 16 nodes (cols4 = w*8 + (lane&7),
// tn = lane>>3 -> 2 nodes/thread). Each weight dwordx4 now touches 128 B
// of unique contiguous data (2 lines) instead of 512 B (8 lines), and the
// 4 waves of a block collectively read the 128 KB weight set exactly once
// (was 4x256 KB requested). Cuts per-CU L1 weight-return traffic ~4-8x,
// which was competing with the gather's L1 path.
#define FMA4(ACC, W, S) ACC.x += W.x * (S); ACC.y += W.y * (S); \
                        ACC.z += W.z * (S); ACC.w += W.w * (S);

__global__ void sage_layer(const float* __restrict__ xin, float* __restrict__ xout,
                           const int* __restrict__ row_start, const int* __restrict__ csr,
                           const float* __restrict__ inv_deg,
                           const float* __restrict__ Wlt, const float* __restrict__ Wrt,
                           const float* __restrict__ bl, int n_nodes) {
    __shared__ __align__(16) float A[TM][DP];
    __shared__ __align__(16) float X[TM][DP];
    int block0 = blockIdx.x * TM;
    int tid = threadIdx.x;

    // Phase A: one wave per node (4 nodes/wave sequentially). Two 32-lane
    // halves walk alternate edges with a 4-deep float4 pipeline each ->
    // 8 row loads in flight per wave. All threads reach the barrier.
    {
        int lane = tid & 63;
        int w    = tid >> 6;      // wave 0..3
        int h    = lane >> 5;     // half 0/1
        int sl   = lane & 31;     // sub-lane within half
        const char* xbase = (const char*)xin;
        int laneoff = sl * 16;

        for (int t = 0; t < 4; ++t) {
            int j = w * 4 + t;
            int n = block0 + j;
            float4 s0 = {0,0,0,0}, s1 = {0,0,0,0}, s2 = {0,0,0,0}, s3 = {0,0,0,0};
            float idg = 1.f;
            float2 xv = {0.f, 0.f};
            int e0 = 0, e1 = 0;
            if (n < n_nodes) {
                e0 = row_start[n];
                e1 = row_start[n + 1];
                idg = inv_deg[n];
                xv = ((const float2*)(xin + (size_t)n * D))[lane];
            }
            ((float2*)X[j])[lane] = xv;

            int e = e0 + h;
            for (; e + 6 < e1; e += 8) {
                int o0i = csr[e], o1i = csr[e + 2], o2i = csr[e + 4], o3i = csr[e + 6];
                float4 v0 = *(const float4*)(xbase + (size_t)(o0i + laneoff));
                float4 v1 = *(const float4*)(xbase + (size_t)(o1i + laneoff));
                float4 v2 = *(const float4*)(xbase + (size_t)(o2i + laneoff));
                float4 v3 = *(const float4*)(xbase + (size_t)(o3i + laneoff));
                s0.x += v0.x; s0.y += v0.y; s0.z += v0.z; s0.w += v0.w;
                s1.x += v1.x; s1.y += v1.y; s1.z += v1.z; s1.w += v1.w;
                s2.x += v2.x; s2.y += v2.y; s2.z += v2.z; s2.w += v2.w;
                s3.x += v3.x; s3.y += v3.y; s3.z += v3.z; s3.w += v3.w;
            }
            for (; e < e1; e += 2) {
                int o0i = csr[e];
                float4 v0 = *(const float4*)(xbase + (size_t)(o0i + laneoff));
                s0.x += v0.x; s0.y += v0.y; s0.z += v0.z; s0.w += v0.w;
            }

            float4 s;
            s.x = (s0.x + s1.x) + (s2.x + s3.x);
            s.y = (s0.y + s1.y) + (s2.y + s3.y);
            s.z = (s0.z + s1.z) + (s2.z + s3.z);
            s.w = (s0.w + s1.w) + (s2.w + s3.w);
            s.x += __shfl_down(s.x, 32);
            s.y += __shfl_down(s.y, 32);
            s.z += __shfl_down(s.z, 32);
            s.w += __shfl_down(s.w, 32);
            if (h == 0) {
                float4 r;
                r.x = s.x * idg; r.y = s.y * idg; r.z = s.z * idg; r.w = s.w * idg;
                ((float4*)A[j])[sl] = r;
            }
        }
    }
    __syncthreads();

    // Phase B: wave w owns feature float4-columns [w*8, w*8+8) for all 16
    // nodes. Thread = 8 features x 2 nodes, k-step 4, chained fmacs.
    {
        int lane = tid & 63;
        int w    = tid >> 6;
        int c8   = lane & 7;        // float4 col within wave slice
        int tn   = lane >> 3;       // 0..7
        int cols4 = w * 8 + c8;     // global float4 col 0..31
        int j0 = tn * 2, j1 = j0 + 1;
        const float4* wlp = (const float4*)Wlt + cols4;   // row k at wlp[k*32]
        const float4* wrp = (const float4*)Wrt + cols4;
        float4 bv = ((const float4*)bl)[cols4];
        float4 acc0 = bv, acc1 = bv;
        const float* Arow0 = A[j0];
        const float* Arow1 = A[j1];
        const float* Xrow0 = X[j0];
        const float* Xrow1 = X[j1];

        for (int k = 0; k < D; k += 4) {
            float4 wl0 = wlp[(k + 0) * 32];
            float4 wl1 = wlp[(k + 1) * 32];
            float4 wl2 = wlp[(k + 2) * 32];
            float4 wl3 = wlp[(k + 3) * 32];
            float4 wr0 = wrp[(k + 0) * 32];
            float4 wr1 = wrp[(k + 1) * 32];
            float4 wr2 = wrp[(k + 2) * 32];
            float4 wr3 = wrp[(k + 3) * 32];
            float4 a0 = *(const float4*)&Arow0[k];
            float4 a1 = *(const float4*)&Arow1[k];
            float4 x0 = *(const float4*)&Xrow0[k];
            float4 x1 = *(const float4*)&Xrow1[k];

            FMA4(acc0, wl0, a0.x) FMA4(acc0, wl1, a0.y)
            FMA4(acc0, wl2, a0.z) FMA4(acc0, wl3, a0.w)
            FMA4(acc0, wr0, x0.x) FMA4(acc0, wr1, x0.y)
            FMA4(acc0, wr2, x0.z) FMA4(acc0, wr3, x0.w)
            FMA4(acc1, wl0, a1.x) FMA4(acc1, wl1, a1.y)
            FMA4(acc1, wl2, a1.z) FMA4(acc1, wl3, a1.w)
            FMA4(acc1, wr0, x1.x) FMA4(acc1, wr1, x1.y)
            FMA4(acc1, wr2, x1.z) FMA4(acc1, wr3, x1.w)
        }

        int n0 = block0 + j0, n1 = block0 + j1;
        if (n0 < n_nodes) {
            float4 r;
            r.x = fmaxf(acc0.x, 0.f); r.y = fmaxf(acc0.y, 0.f);
            r.z = fmaxf(acc0.z, 0.f); r.w = fmaxf(acc0.w, 0.f);
            ((float4*)xout)[(size_t)n0 * 32 + cols4] = r;
        }
        if (n1 < n_nodes) {
            float4 r;
            r.x = fmaxf(acc1.x, 0.f); r.y = fmaxf(acc1.y, 0.f);
            r.z = fmaxf(acc1.z, 0.f); r.w = fmaxf(acc1.w, 0.f);
            ((float4*)xout)[(size_t)n1 * 32 + cols4] = r;
        }
    }
}

extern "C" void kernel_launch(void* const* d_in, const int* in_sizes, int n_in,
                              void* d_out, int out_size, void* d_ws, size_t ws_size,
                              hipStream_t stream) {
    const float* x  = (const float*)d_in[0];
    const int*  edge = (const int*)d_in[1];
    const float* Wl = (const float*)d_in[2];
    const float* bl = (const float*)d_in[3];
    const float* Wr = (const float*)d_in[4];

    int N = in_sizes[0] / D;
    int E = in_sizes[1] / 2;
    int L = in_sizes[3] / D;
    const int* srcp = edge;
    const int* dstp = edge + E;

    char* w = (char*)d_ws;
    auto alloc = [&](size_t bytes) {
        char* p = w;
        w += (bytes + 255) & ~(size_t)255;
        return p;
    };
    int*   deg       = (int*)alloc((size_t)N * 4);
    int*   local_ex  = (int*)alloc((size_t)N * 4);
    int*   row_start = (int*)alloc((size_t)(N + 1) * 4);
    int*   cursor    = (int*)alloc((size_t)N * 4);
    int*   csr       = (int*)alloc((size_t)E * 4);
    float* invdeg    = (float*)alloc((size_t)N * 4);
    int*   blocksum  = (int*)alloc((size_t)1024 * 4);
    float* wlt       = (float*)alloc((size_t)L * D * D * 4);
    float* wrt       = (float*)alloc((size_t)L * D * D * 4);
    float* buf0      = (float*)alloc((size_t)N * D * 4);

    int nb1 = (N + 1023) / 1024;
    hipMemsetAsync(deg, 0, (size_t)N * 4, stream);
    hist_kernel<<<(E + 255) / 256, 256, 0, stream>>>(dstp, deg, E);
    scan1_kernel<<<nb1, 1024, 0, stream>>>(deg, local_ex, blocksum, N);
    scan2_kernel<<<1, 1024, 0, stream>>>(blocksum, nb1);
    scan3_kernel<<<nb1, 1024, 0, stream>>>(deg, local_ex, blocksum, row_start,
                                           cursor, invdeg, N, E);
    scatter_kernel<<<(E + 255) / 256, 256, 0, stream>>>(srcp, dstp, cursor, csr, E);
    int tw = L * D * D;
    transpose_w<<<(tw + 255) / 256, 256, 0, stream>>>(Wl, Wr, wlt, wrt, tw);

    float* out = (float*)d_out;
    const float* cur = x;
    int nbl = (N + TM - 1) / TM;
    for (int l = 0; l < L; ++l) {
        float* o = (l & 1) ? out : buf0;
        if (l == L - 1) o = out;
        sage_layer<<<nbl, 256, 0, stream>>>(cur, o, row_start, csr, invdeg,
                                            wlt + (size_t)l * D * D,
                                            wrt + (size_t)l * D * D,
                                            bl + (size_t)l * D, N);
        cur = o;
    }
}

// Round 2
// 1170.443 us; speedup vs baseline: 1.1057x; 1.1057x over previous
//
#include <hip/hip_runtime.h>
#include <hip/hip_fp16.h>

#define D 128
#define DP 132  // LDS row stride (floats): +4 pad; 528B row stays 16B-aligned.
#define TM 16   // fused layer tile: 16 nodes, ~16.5 KB LDS -> 8 blocks/CU

// ---------------- CSR build ----------------

__global__ void hist_kernel(const int* __restrict__ dst, int* __restrict__ deg, int E) {
    int i = blockIdx.x * blockDim.x + threadIdx.x;
    if (i < E) atomicAdd(&deg[dst[i]], 1);
}

__global__ void scan1_kernel(const int* __restrict__ deg, int* __restrict__ local_excl,
                             int* __restrict__ blocksum, int n) {
    __shared__ int tmp[1024];
    int i = blockIdx.x * 1024 + threadIdx.x;
    int v = (i < n) ? deg[i] : 0;
    tmp[threadIdx.x] = v;
    __syncthreads();
    for (int off = 1; off < 1024; off <<= 1) {
        int t = 0;
        if (threadIdx.x >= off) t = tmp[threadIdx.x - off];
        __syncthreads();
        if (threadIdx.x >= off) tmp[threadIdx.x] += t;
        __syncthreads();
    }
    int incl = tmp[threadIdx.x];
    if (i < n) local_excl[i] = incl - v;
    if (threadIdx.x == 1023) blocksum[blockIdx.x] = tmp[1023];
}

__global__ void scan2_kernel(int* __restrict__ blocksum, int nb) {
    __shared__ int tmp[1024];
    int v = (threadIdx.x < nb) ? blocksum[threadIdx.x] : 0;
    tmp[threadIdx.x] = v;
    __syncthreads();
    for (int off = 1; off < 1024; off <<= 1) {
        int t = 0;
        if (threadIdx.x >= off) t = tmp[threadIdx.x - off];
        __syncthreads();
        if (threadIdx.x >= off) tmp[threadIdx.x] += t;
        __syncthreads();
    }
    if (threadIdx.x < nb) blocksum[threadIdx.x] = tmp[threadIdx.x] - v;  // exclusive
}

__global__ void scan3_kernel(const int* __restrict__ deg, const int* __restrict__ local_excl,
                             const int* __restrict__ blocksum, int* __restrict__ row_start,
                             int* __restrict__ cursor, float* __restrict__ inv_deg,
                             int n, int n_edges) {
    int i = blockIdx.x * 1024 + threadIdx.x;
    if (i < n) {
        int rs = local_excl[i] + blocksum[blockIdx.x];
        row_start[i] = rs;
        cursor[i]    = rs;
        inv_deg[i]   = 1.0f / fmaxf((float)deg[i], 1.0f);
    }
    if (i == 0) row_start[n] = n_edges;
}

// csr[] holds BYTE offsets of the fp16 source row (src * D * 2 = src * 256).
__global__ void scatter_kernel(const int* __restrict__ src, const int* __restrict__ dst,
                               int* __restrict__ cursor, int* __restrict__ csr, int E) {
    int i = blockIdx.x * blockDim.x + threadIdx.x;
    if (i < E) {
        int d = dst[i];
        int p = atomicAdd(&cursor[d], 1);
        csr[p] = src[i] << 8;   // * 256 bytes per fp16 row
    }
}

// ---------------- weight transpose (W[l][f][k] -> Wt[l][k][f]) ----------------

__global__ void transpose_w(const float* __restrict__ Wl, const float* __restrict__ Wr,
                            float* __restrict__ Wlt, float* __restrict__ Wrt, int total) {
    int i = blockIdx.x * blockDim.x + threadIdx.x;
    if (i < total) {
        int l = i >> 14;
        int r = i & 16383;
        int f = r >> 7;
        int k = r & 127;
        int o = (l << 14) + (k << 7) + f;
        Wlt[o] = Wl[i];
        Wrt[o] = Wr[i];
    }
}

// ---------------- initial fp32 -> fp16 shadow copy ----------------

__global__ void x_to_half(const float* __restrict__ x, __half* __restrict__ xh, int total4) {
    int i = blockIdx.x * blockDim.x + threadIdx.x;   // one float4 per thread
    if (i < total4) {
        float4 v = ((const float4*)x)[i];
        __half2 h0 = __float22half2_rn(make_float2(v.x, v.y));
        __half2 h1 = __float22half2_rn(make_float2(v.z, v.w));
        uint2 u;
        u.x = *(unsigned int*)&h0;
        u.y = *(unsigned int*)&h1;
        ((uint2*)xh)[i] = u;
    }
}

// ---------------- fused SAGE layer ----------------
// Phase A (r11 change): gather from an fp16 shadow of x. A 256B fp16 row is
// read by a 16-lane group (16B/lane dwordx4), so each wave-instruction still
// touches 16 cache lines (same line-MLP as the fp32 version) but covers 4
// edges instead of 2. 4-deep pipeline covers 16 edges/iter; remainder is a
// single clamped+masked 4-deep pass (still 4 loads in flight, no 1-deep
// tail). Halves L2-miss traffic on the random-gather path, which r10's
// post-mortem showed is the whole critical path.
// Phase B: feature-sliced waves (r10), fp32 GEMM from LDS, unchanged math;
// epilogue also writes the fp16 shadow for the next layer (ping-pong buffer
// to avoid same-kernel read/write race).
#define FMA4(ACC, W, S) ACC.x += W.x * (S); ACC.y += W.y * (S); \
                        ACC.z += W.z * (S); ACC.w += W.w * (S);

// Accumulate 8 fp16 features (one dwordx4) into sA/sB fp32 accumulators.
#define ACC8(V) { const __half2* hp_ = (const __half2*)&(V);                 \
    float2 f0_ = __half22float2(hp_[0]); float2 f1_ = __half22float2(hp_[1]);\
    float2 f2_ = __half22float2(hp_[2]); float2 f3_ = __half22float2(hp_[3]);\
    sA.x += f0_.x; sA.y += f0_.y; sA.z += f1_.x; sA.w += f1_.y;              \
    sB.x += f2_.x; sB.y += f2_.y; sB.z += f3_.x; sB.w += f3_.y; }

__global__ void sage_layer(const float* __restrict__ xin,
                           const __half* __restrict__ xh_in,
                           float* __restrict__ xout,
                           __half* __restrict__ xh_out,
                           const int* __restrict__ row_start, const int* __restrict__ csr,
                           const float* __restrict__ inv_deg,
                           const float* __restrict__ Wlt, const float* __restrict__ Wrt,
                           const float* __restrict__ bl, int n_nodes) {
    __shared__ __align__(16) float A[TM][DP];
    __shared__ __align__(16) float X[TM][DP];
    int block0 = blockIdx.x * TM;
    int tid = threadIdx.x;

    // Phase A: one wave per node (4 nodes/wave sequentially). Four 16-lane
    // groups each own one edge per pipeline slot; 4 slots -> 16 edges/iter,
    // 4 dwordx4 gather instructions in flight per wave.
    {
        int lane = tid & 63;
        int w    = tid >> 6;      // wave 0..3
        int g    = lane >> 4;     // 16-lane group 0..3
        int sub  = lane & 15;     // lane within group
        const char* hbase = (const char*)xh_in;
        int laneoff = sub * 16;   // 16B per lane within 256B row

        for (int t = 0; t < 4; ++t) {
            int j = w * 4 + t;
            int n = block0 + j;
            float4 sA = {0,0,0,0}, sB = {0,0,0,0};
            float idg = 1.f;
            float2 xv = {0.f, 0.f};
            int e0 = 0, e1 = 0;
            if (n < n_nodes) {
                e0 = row_start[n];
                e1 = row_start[n + 1];
                idg = inv_deg[n];
                xv = ((const float2*)(xin + (size_t)n * D))[lane];
            }
            ((float2*)X[j])[lane] = xv;

            int eb = e0;
            for (; eb + 16 <= e1; eb += 16) {
                int i0 = csr[eb + g];
                int i1 = csr[eb + g + 4];
                int i2 = csr[eb + g + 8];
                int i3 = csr[eb + g + 12];
                float4 v0 = *(const float4*)(hbase + (size_t)(i0 + laneoff));
                float4 v1 = *(const float4*)(hbase + (size_t)(i1 + laneoff));
                float4 v2 = *(const float4*)(hbase + (size_t)(i2 + laneoff));
                float4 v3 = *(const float4*)(hbase + (size_t)(i3 + laneoff));
                ACC8(v0) ACC8(v1) ACC8(v2) ACC8(v3)
            }
            if (eb < e1) {
                // clamped + masked single pass: up to 15 remaining edges,
                // still 4 loads in flight.
                int last = e1 - 1;
                int b0 = eb + g, b1 = b0 + 4, b2 = b0 + 8, b3 = b0 + 12;
                int c0 = min(b0, last), c1 = min(b1, last);
                int c2 = min(b2, last), c3 = min(b3, last);
                int i0 = csr[c0], i1 = csr[c1], i2 = csr[c2], i3 = csr[c3];
                float4 v0 = *(const float4*)(hbase + (size_t)(i0 + laneoff));
                float4 v1 = *(const float4*)(hbase + (size_t)(i1 + laneoff));
                float4 v2 = *(const float4*)(hbase + (size_t)(i2 + laneoff));
                float4 v3 = *(const float4*)(hbase + (size_t)(i3 + laneoff));
                if (b0 <= last) ACC8(v0)
                if (b1 <= last) ACC8(v1)
                if (b2 <= last) ACC8(v2)
                if (b3 <= last) ACC8(v3)
            }

            // reduce across the 4 groups (lane bits 4,5)
            sA.x += __shfl_xor(sA.x, 16); sA.x += __shfl_xor(sA.x, 32);
            sA.y += __shfl_xor(sA.y, 16); sA.y += __shfl_xor(sA.y, 32);
            sA.z += __shfl_xor(sA.z, 16); sA.z += __shfl_xor(sA.z, 32);
            sA.w += __shfl_xor(sA.w, 16); sA.w += __shfl_xor(sA.w, 32);
            sB.x += __shfl_xor(sB.x, 16); sB.x += __shfl_xor(sB.x, 32);
            sB.y += __shfl_xor(sB.y, 16); sB.y += __shfl_xor(sB.y, 32);
            sB.z += __shfl_xor(sB.z, 16); sB.z += __shfl_xor(sB.z, 32);
            sB.w += __shfl_xor(sB.w, 16); sB.w += __shfl_xor(sB.w, 32);
            if (g == 0) {
                sA.x *= idg; sA.y *= idg; sA.z *= idg; sA.w *= idg;
                sB.x *= idg; sB.y *= idg; sB.z *= idg; sB.w *= idg;
                ((float4*)A[j])[sub * 2]     = sA;
                ((float4*)A[j])[sub * 2 + 1] = sB;
            }
        }
    }
    __syncthreads();

    // Phase B: wave w owns feature float4-columns [w*8, w*8+8) for all 16
    // nodes. Thread = 8 features x 2 nodes, k-step 4, chained fmacs.
    {
        int lane = tid & 63;
        int w    = tid >> 6;
        int c8   = lane & 7;        // float4 col within wave slice
        int tn   = lane >> 3;       // 0..7
        int cols4 = w * 8 + c8;     // global float4 col 0..31
        int j0 = tn * 2, j1 = j0 + 1;
        const float4* wlp = (const float4*)Wlt + cols4;   // row k at wlp[k*32]
        const float4* wrp = (const float4*)Wrt + cols4;
        float4 bv = ((const float4*)bl)[cols4];
        float4 acc0 = bv, acc1 = bv;
        const float* Arow0 = A[j0];
        const float* Arow1 = A[j1];
        const float* Xrow0 = X[j0];
        const float* Xrow1 = X[j1];

        for (int k = 0; k < D; k += 4) {
            float4 wl0 = wlp[(k + 0) * 32];
            float4 wl1 = wlp[(k + 1) * 32];
            float4 wl2 = wlp[(k + 2) * 32];
            float4 wl3 = wlp[(k + 3) * 32];
            float4 wr0 = wrp[(k + 0) * 32];
            float4 wr1 = wrp[(k + 1) * 32];
            float4 wr2 = wrp[(k + 2) * 32];
            float4 wr3 = wrp[(k + 3) * 32];
            float4 a0 = *(const float4*)&Arow0[k];
            float4 a1 = *(const float4*)&Arow1[k];
            float4 x0 = *(const float4*)&Xrow0[k];
            float4 x1 = *(const float4*)&Xrow1[k];

            FMA4(acc0, wl0, a0.x) FMA4(acc0, wl1, a0.y)
            FMA4(acc0, wl2, a0.z) FMA4(acc0, wl3, a0.w)
            FMA4(acc0, wr0, x0.x) FMA4(acc0, wr1, x0.y)
            FMA4(acc0, wr2, x0.z) FMA4(acc0, wr3, x0.w)
            FMA4(acc1, wl0, a1.x) FMA4(acc1, wl1, a1.y)
            FMA4(acc1, wl2, a1.z) FMA4(acc1, wl3, a1.w)
            FMA4(acc1, wr0, x1.x) FMA4(acc1, wr1, x1.y)
            FMA4(acc1, wr2, x1.z) FMA4(acc1, wr3, x1.w)
        }

        int n0 = block0 + j0, n1 = block0 + j1;
        if (n0 < n_nodes) {
            float4 r;
            r.x = fmaxf(acc0.x, 0.f); r.y = fmaxf(acc0.y, 0.f);
            r.z = fmaxf(acc0.z, 0.f); r.w = fmaxf(acc0.w, 0.f);
            ((float4*)xout)[(size_t)n0 * 32 + cols4] = r;
            __half2 h0 = __float22half2_rn(make_float2(r.x, r.y));
            __half2 h1 = __float22half2_rn(make_float2(r.z, r.w));
            uint2 u;
            u.x = *(unsigned int*)&h0;
            u.y = *(unsigned int*)&h1;
            ((uint2*)xh_out)[(size_t)n0 * 32 + cols4] = u;
        }
        if (n1 < n_nodes) {
            float4 r;
            r.x = fmaxf(acc1.x, 0.f); r.y = fmaxf(acc1.y, 0.f);
            r.z = fmaxf(acc1.z, 0.f); r.w = fmaxf(acc1.w, 0.f);
            ((float4*)xout)[(size_t)n1 * 32 + cols4] = r;
            __half2 h0 = __float22half2_rn(make_float2(r.x, r.y));
            __half2 h1 = __float22half2_rn(make_float2(r.z, r.w));
            uint2 u;
            u.x = *(unsigned int*)&h0;
            u.y = *(unsigned int*)&h1;
            ((uint2*)xh_out)[(size_t)n1 * 32 + cols4] = u;
        }
    }
}

extern "C" void kernel_launch(void* const* d_in, const int* in_sizes, int n_in,
                              void* d_out, int out_size, void* d_ws, size_t ws_size,
                              hipStream_t stream) {
    const float* x  = (const float*)d_in[0];
    const int*  edge = (const int*)d_in[1];
    const float* Wl = (const float*)d_in[2];
    const float* bl = (const float*)d_in[3];
    const float* Wr = (const float*)d_in[4];

    int N = in_sizes[0] / D;
    int E = in_sizes[1] / 2;
    int L = in_sizes[3] / D;
    const int* srcp = edge;
    const int* dstp = edge + E;

    char* w = (char*)d_ws;
    auto alloc = [&](size_t bytes) {
        char* p = w;
        w += (bytes + 255) & ~(size_t)255;
        return p;
    };
    int*   deg       = (int*)alloc((size_t)N * 4);
    int*   local_ex  = (int*)alloc((size_t)N * 4);
    int*   row_start = (int*)alloc((size_t)(N + 1) * 4);
    int*   cursor    = (int*)alloc((size_t)N * 4);
    int*   csr       = (int*)alloc((size_t)E * 4);
    float* invdeg    = (float*)alloc((size_t)N * 4);
    int*   blocksum  = (int*)alloc((size_t)1024 * 4);
    float* wlt       = (float*)alloc((size_t)L * D * D * 4);
    float* wrt       = (float*)alloc((size_t)L * D * D * 4);
    float* buf0      = (float*)alloc((size_t)N * D * 4);
    __half* xh0      = (__half*)alloc((size_t)N * D * 2);
    __half* xh1      = (__half*)alloc((size_t)N * D * 2);

    int nb1 = (N + 1023) / 1024;
    hipMemsetAsync(deg, 0, (size_t)N * 4, stream);
    hist_kernel<<<(E + 255) / 256, 256, 0, stream>>>(dstp, deg, E);
    scan1_kernel<<<nb1, 1024, 0, stream>>>(deg, local_ex, blocksum, N);
    scan2_kernel<<<1, 1024, 0, stream>>>(blocksum, nb1);
    scan3_kernel<<<nb1, 1024, 0, stream>>>(deg, local_ex, blocksum, row_start,
                                           cursor, invdeg, N, E);
    scatter_kernel<<<(E + 255) / 256, 256, 0, stream>>>(srcp, dstp, cursor, csr, E);
    int tw = L * D * D;
    transpose_w<<<(tw + 255) / 256, 256, 0, stream>>>(Wl, Wr, wlt, wrt, tw);
    int t4 = N * (D / 4);
    x_to_half<<<(t4 + 255) / 256, 256, 0, stream>>>(x, xh0, t4);

    float* out = (float*)d_out;
    const float* cur = x;
    int nbl = (N + TM - 1) / TM;
    for (int l = 0; l < L; ++l) {
        float* o = (l & 1) ? out : buf0;
        if (l == L - 1) o = out;
        __half* hin  = (l & 1) ? xh1 : xh0;
        __half* hout = (l & 1) ? xh0 : xh1;
        sage_layer<<<nbl, 256, 0, stream>>>(cur, hin, o, hout, row_start, csr, invdeg,
                                            wlt + (size_t)l * D * D,
                                            wrt + (size_t)l * D * D,
                                            bl + (size_t)l * D, N);
        cur = o;
    }
}